// Round 10
// baseline (177.540 us; speedup 1.0000x reference)
//
#include <hip/hip_runtime.h>

// Problem constants: B=16, C=512, H=W=14 (HW=196), D=8000.
#define B_DIM 16
#define C_DIM 512
#define HW_DIM 196
#define D_DIM 8000
#define KP 224                      // K padded to 7*32 for MFMA 16x16x32
#define NROW (B_DIM * C_DIM)        // 8192 rows in xp

typedef __attribute__((ext_vector_type(8))) short short8;   // 8 bf16 frag
typedef __attribute__((ext_vector_type(4))) float float4v;  // 4 f32 acc

// ---------------------------------------------------------------------------
// Kernel 1 (prep), 1024 blocks:
//  blocks 0..511:    extract (hash,sign) of 2 rows of S1|S2 (chunked
//                    early-exit scan).
//  blocks 512..1023: convert 16 rows of x fp32 -> bf16 (K padded to 224);
//                    blocks 512..636 also zero out[16,8000] (for the atomic
//                    flush in kernel 2 — no separate memset dispatch).
// NOTE (R8 lesson): no device-scope fences / inter-block sync anywhere —
// agent-scope release drains the per-XCD L2 (~70 us). Dispatch boundaries
// provide the needed ordering.
// ---------------------------------------------------------------------------
__global__ __launch_bounds__(256) void prep(
    const float* __restrict__ x, const float* __restrict__ S1,
    const float* __restrict__ S2,
    int* __restrict__ h, float* __restrict__ s,
    unsigned short* __restrict__ xp, float* __restrict__ out) {
    const int bid = blockIdx.x;
    const int tid = threadIdx.x;
    if (bid < 512) {
        __shared__ int found;
        for (int rr = 0; rr < 2; ++rr) {
            const int r     = bid * 2 + rr;
            const int row   = r & (C_DIM - 1);
            const int which = r >> 9;
            const float4* rowp = (const float4*)((which ? S2 : S1) + (size_t)row * D_DIM);
            int*   hp = h + which * C_DIM;
            float* sp = s + which * C_DIM;
            if (tid == 0) found = 0;
            __syncthreads();
            for (int c = 0; c < 8; ++c) {            // 8 chunks of 256 float4
                int j4 = c * 256 + tid;
                if (j4 < D_DIM / 4) {
                    float4 v = rowp[j4];
                    if (v.x != 0.f) { hp[row] = 4 * j4 + 0; sp[row] = v.x; found = 1; }
                    if (v.y != 0.f) { hp[row] = 4 * j4 + 1; sp[row] = v.y; found = 1; }
                    if (v.z != 0.f) { hp[row] = 4 * j4 + 2; sp[row] = v.z; found = 1; }
                    if (v.w != 0.f) { hp[row] = 4 * j4 + 3; sp[row] = v.w; found = 1; }
                }
                __syncthreads();
                if (found) break;                    // uniform after barrier
            }
            __syncthreads();                         // order vs next reset
        }
    } else {
        const int j = bid - 512;                     // 0..511, 16 rows each
        if (j < 125)                                 // 125*256 = 32000 float4
            ((float4*)out)[j * 256 + tid] = (float4){0.f, 0.f, 0.f, 0.f};
        #pragma unroll
        for (int l = 0; l < 14; ++l) {               // 14*256 = 3584 = 16*224
            int idx = l * 256 + tid;
            int r   = idx / KP;
            int kk  = idx - r * KP;
            int row = j * 16 + r;
            float v = (kk < HW_DIM) ? x[(size_t)row * HW_DIM + kk] : 0.0f;
            unsigned int u = __float_as_uint(v);     // RNE fp32 -> bf16
            u = (u + 0x7FFFu + ((u >> 16) & 1u)) >> 16;
            xp[(size_t)row * KP + kk] = (unsigned short)u;
        }
    }
}

// ---------------------------------------------------------------------------
// Kernel 2: barrier-free MFMA Gram + LDS-histogram scatter, one 128x512 slab
// per block (4 blocks per batch). 1024 threads = 16 waves = 4 waves/SIMD;
// each wave runs the proven 32x64 wave-tile twice (32 tiles per slab).
// Flush: 8000 coalesced global atomicAdd per block straight into out —
// no partials, no reduce kernel, no fences.
// Grid: 64 blocks. LDS = 32 KB histogram only.
// ---------------------------------------------------------------------------
__global__ __launch_bounds__(1024, 4) void gram_hist(
    const unsigned short* __restrict__ xp,   // [B*C, KP] bf16 bits
    const int* __restrict__ h, const float* __restrict__ s,
    float* __restrict__ out) {               // [B, D] (zeroed by prep)
    const int b = blockIdx.x >> 2;           // batch
    const int q = blockIdx.x & 3;            // i-quarter: rows [q*128, +128)
    const int tid = threadIdx.x;

    __shared__ __align__(16) float hist[D_DIM];
    #pragma unroll
    for (int l4 = 0; l4 < 2; ++l4) {
        int i4 = l4 * 1024 + tid;
        if (i4 < D_DIM / 4)
            ((float4*)hist)[i4] = (float4){0.f, 0.f, 0.f, 0.f};
    }
    __syncthreads();

    const int w  = tid >> 6;    // wave 0..15
    const int l  = tid & 63;
    const int rA = l & 15;      // fragment row within 16x16 tile
    const int g  = l >> 4;      // k-group: 8 contiguous k at g*8

    const unsigned short* base = xp + (size_t)b * C_DIM * KP;

    #pragma unroll
    for (int pass = 0; pass < 2; ++pass) {
        const int t  = w + pass * 16;        // wave-tile 0..31 = 4(i) x 8(j)
        const int it = t & 3;
        const int jt = t >> 2;
        const int i0 = q * 128 + it * 32;
        const int j0 = jt * 64;

        const unsigned short* pA[2];
        const unsigned short* pB[4];
        #pragma unroll
        for (int mt = 0; mt < 2; ++mt)
            pA[mt] = base + (size_t)(i0 + mt * 16 + rA) * KP + g * 8;
        #pragma unroll
        for (int nt = 0; nt < 4; ++nt)
            pB[nt] = base + (size_t)(j0 + nt * 16 + rA) * KP + g * 8;

        float4v acc[2][4];
        #pragma unroll
        for (int mt = 0; mt < 2; ++mt)
            #pragma unroll
            for (int nt = 0; nt < 4; ++nt)
                acc[mt][nt] = (float4v){0.0f, 0.0f, 0.0f, 0.0f};

        short8 fa[2], fb[4];
        #pragma unroll
        for (int mt = 0; mt < 2; ++mt) fa[mt] = *(const short8*)pA[mt];
        #pragma unroll
        for (int nt = 0; nt < 4; ++nt) fb[nt] = *(const short8*)pB[nt];

        // 7 K-steps of 32; register double-buffered prefetch; zero barriers.
        #pragma unroll
        for (int step = 1; step <= 7; ++step) {
            short8 na[2], nb[4];
            if (step < 7) {
                #pragma unroll
                for (int mt = 0; mt < 2; ++mt) na[mt] = *(const short8*)(pA[mt] + step * 32);
                #pragma unroll
                for (int nt = 0; nt < 4; ++nt) nb[nt] = *(const short8*)(pB[nt] + step * 32);
            }
            #pragma unroll
            for (int mt = 0; mt < 2; ++mt)
                #pragma unroll
                for (int nt = 0; nt < 4; ++nt)
                    acc[mt][nt] = __builtin_amdgcn_mfma_f32_16x16x32_bf16(
                        fa[mt], fb[nt], acc[mt][nt], 0, 0, 0);
            if (step < 7) {
                #pragma unroll
                for (int mt = 0; mt < 2; ++mt) fa[mt] = na[mt];
                #pragma unroll
                for (int nt = 0; nt < 4; ++nt) fb[nt] = nb[nt];
            }
        }

        // Scatter: C/D layout col = lane&15, row = (lane>>4)*4 + reg.
        int hr[2][4]; float sr[2][4]; int hc[4]; float sc[4];
        #pragma unroll
        for (int mt = 0; mt < 2; ++mt)
            #pragma unroll
            for (int rg = 0; rg < 4; ++rg) {
                int c1 = i0 + mt * 16 + (l >> 4) * 4 + rg;
                hr[mt][rg] = h[c1]; sr[mt][rg] = s[c1];
            }
        #pragma unroll
        for (int nt = 0; nt < 4; ++nt) {
            int c2 = j0 + nt * 16 + (l & 15);
            hc[nt] = h[C_DIM + c2]; sc[nt] = s[C_DIM + c2];
        }
        #pragma unroll
        for (int mt = 0; mt < 2; ++mt)
            #pragma unroll
            for (int nt = 0; nt < 4; ++nt)
                #pragma unroll
                for (int rg = 0; rg < 4; ++rg) {
                    int bin = hr[mt][rg] + hc[nt];
                    if (bin >= D_DIM) bin -= D_DIM;
                    atomicAdd(&hist[bin], sr[mt][rg] * sc[nt] * acc[mt][nt][rg]);
                }
    }
    __syncthreads();

    // Flush: coalesced global atomics into out (4 blocks add per batch).
    float* outb = out + (size_t)b * D_DIM;
    #pragma unroll
    for (int l4 = 0; l4 < 8; ++l4) {
        int d = l4 * 1024 + tid;
        if (d < D_DIM) atomicAdd(outb + d, hist[d]);
    }
}

extern "C" void kernel_launch(void* const* d_in, const int* in_sizes, int n_in,
                              void* d_out, int out_size, void* d_ws, size_t ws_size,
                              hipStream_t stream) {
    const float* x  = (const float*)d_in[0];  // [16, 512, 14, 14] fp32
    const float* S1 = (const float*)d_in[1];  // [512, 8000] fp32
    const float* S2 = (const float*)d_in[2];  // [512, 8000] fp32
    float* out = (float*)d_out;               // [16, 8000] fp32

    // ws: h[1024] int | s[1024] f32 | xp[8192*224] bf16 (3.7 MB)
    int*            h  = (int*)d_ws;
    float*          s  = (float*)(h + 2 * C_DIM);
    unsigned short* xp = (unsigned short*)(s + 2 * C_DIM);

    prep<<<1024, 256, 0, stream>>>(x, S1, S2, h, s, xp, out);

    gram_hist<<<64, 1024, 0, stream>>>(xp, h, s, out);
}

// Round 11
// 113.735 us; speedup vs baseline: 1.5610x; 1.5610x over previous
//
#include <hip/hip_runtime.h>

// Problem constants: B=16, C=512, H=W=14 (HW=196), D=8000.
#define B_DIM 16
#define C_DIM 512
#define HW_DIM 196
#define D_DIM 8000
#define KP 224                      // K padded to 7*32 for MFMA 16x16x32
#define NROW (B_DIM * C_DIM)        // 8192 rows in xp

typedef __attribute__((ext_vector_type(8))) short short8;   // 8 bf16 frag
typedef __attribute__((ext_vector_type(4))) float float4v;  // 4 f32 acc

// ---------------------------------------------------------------------------
// Kernel 1 (prep), 1024 blocks:
//  blocks 0..511:    extract (hash,sign) of 2 rows of S1|S2, chunked
//                    early-exit scan.
//  blocks 512..1023: convert 16 rows of x fp32 -> bf16, pad K 196 -> 224.
// NOTE (R8 lesson): no device-scope fences / inter-block sync anywhere —
// agent-scope release drains the per-XCD L2 (~70 us across 512 blocks).
// NOTE (R7/R10 lesson): grids must cover all 256 CUs with >=2 waves/SIMD.
// ---------------------------------------------------------------------------
__global__ __launch_bounds__(256) void prep(
    const float* __restrict__ x, const float* __restrict__ S1,
    const float* __restrict__ S2,
    int* __restrict__ h, float* __restrict__ s,
    unsigned short* __restrict__ xp) {
    const int bid = blockIdx.x;
    const int tid = threadIdx.x;
    if (bid < 512) {
        __shared__ int found;
        for (int rr = 0; rr < 2; ++rr) {
            const int r     = bid * 2 + rr;
            const int row   = r & (C_DIM - 1);
            const int which = r >> 9;
            const float4* rowp = (const float4*)((which ? S2 : S1) + (size_t)row * D_DIM);
            int*   hp = h + which * C_DIM;
            float* sp = s + which * C_DIM;
            if (tid == 0) found = 0;
            __syncthreads();
            for (int c = 0; c < 8; ++c) {            // 8 chunks of 256 float4
                int j4 = c * 256 + tid;
                if (j4 < D_DIM / 4) {
                    float4 v = rowp[j4];
                    if (v.x != 0.f) { hp[row] = 4 * j4 + 0; sp[row] = v.x; found = 1; }
                    if (v.y != 0.f) { hp[row] = 4 * j4 + 1; sp[row] = v.y; found = 1; }
                    if (v.z != 0.f) { hp[row] = 4 * j4 + 2; sp[row] = v.z; found = 1; }
                    if (v.w != 0.f) { hp[row] = 4 * j4 + 3; sp[row] = v.w; found = 1; }
                }
                __syncthreads();
                if (found) break;                    // uniform after barrier
            }
            __syncthreads();                         // order vs next reset
        }
    } else {
        const int j = bid - 512;                     // 0..511, 16 rows each
        #pragma unroll
        for (int l = 0; l < 14; ++l) {               // 14*256 = 3584 = 16*224
            int idx = l * 256 + tid;
            int r   = idx / KP;
            int kk  = idx - r * KP;
            int row = j * 16 + r;
            float v = (kk < HW_DIM) ? x[(size_t)row * HW_DIM + kk] : 0.0f;
            unsigned int u = __float_as_uint(v);     // RNE fp32 -> bf16
            u = (u + 0x7FFFu + ((u >> 16) & 1u)) >> 16;
            xp[(size_t)row * KP + kk] = (unsigned short)u;
        }
    }
}

// ---------------------------------------------------------------------------
// Kernel 2: barrier-free MFMA Gram, 128x128 block tile, 512 threads =
// 8 waves (4 i x 2 j wave-grid of the proven 32x64 wave tile). All 256 CUs
// covered, 2 waves/SIMD. Half the histograms of R9 -> half the hist-zero,
// flush, and reduce traffic. No global atomics, no fences.
// Grid: (2 j, 4 i... ) -> (4 j, 4 i, 16 b)/2 = (2, 4, 16)? No: 512/128 = 4
// tiles per axis -> grid (4, 4, 16) / wave-j covers 2 tiles? Correct layout:
// grid (4 j-tiles? ) -- block tile is 128x128, C=512 -> 4x4 tiles, 16 b
// => grid (4, 4, 16) = 256 blocks.
// LDS = 32 KB histogram only.
// ---------------------------------------------------------------------------
__global__ __launch_bounds__(512) void gram_hist(
    const unsigned short* __restrict__ xp,   // [B*C, KP] bf16 bits
    const int* __restrict__ h, const float* __restrict__ s,
    float* __restrict__ part) {              // [256, D] partials
    const int jb = blockIdx.x;               // 0..3
    const int ib = blockIdx.y;               // 0..3
    const int b  = blockIdx.z;               // 0..15
    const int tid = threadIdx.x;

    __shared__ __align__(16) float hist[D_DIM];
    #pragma unroll
    for (int l4 = 0; l4 < 4; ++l4) {
        int i4 = l4 * 512 + tid;
        if (i4 < D_DIM / 4)
            ((float4*)hist)[i4] = (float4){0.f, 0.f, 0.f, 0.f};
    }
    __syncthreads();

    const int w  = tid >> 6;    // wave 0..7: iw = w&3, jw = w>>2
    const int l  = tid & 63;
    const int rA = l & 15;      // fragment row within 16x16 tile
    const int g  = l >> 4;      // k-group: 8 contiguous k at g*8

    const int i0 = ib * 128 + (w & 3) * 32;
    const int j0 = jb * 128 + (w >> 2) * 64;

    const unsigned short* base = xp + (size_t)b * C_DIM * KP;
    const unsigned short* pA[2];
    const unsigned short* pB[4];
    #pragma unroll
    for (int mt = 0; mt < 2; ++mt)
        pA[mt] = base + (size_t)(i0 + mt * 16 + rA) * KP + g * 8;
    #pragma unroll
    for (int nt = 0; nt < 4; ++nt)
        pB[nt] = base + (size_t)(j0 + nt * 16 + rA) * KP + g * 8;

    float4v acc[2][4];
    #pragma unroll
    for (int mt = 0; mt < 2; ++mt)
        #pragma unroll
        for (int nt = 0; nt < 4; ++nt)
            acc[mt][nt] = (float4v){0.0f, 0.0f, 0.0f, 0.0f};

    short8 fa[2], fb[4];
    #pragma unroll
    for (int mt = 0; mt < 2; ++mt) fa[mt] = *(const short8*)pA[mt];
    #pragma unroll
    for (int nt = 0; nt < 4; ++nt) fb[nt] = *(const short8*)pB[nt];

    // 7 K-steps of 32; register double-buffered prefetch; zero barriers.
    #pragma unroll
    for (int step = 1; step <= 7; ++step) {
        short8 na[2], nb[4];
        if (step < 7) {
            #pragma unroll
            for (int mt = 0; mt < 2; ++mt) na[mt] = *(const short8*)(pA[mt] + step * 32);
            #pragma unroll
            for (int nt = 0; nt < 4; ++nt) nb[nt] = *(const short8*)(pB[nt] + step * 32);
        }
        #pragma unroll
        for (int mt = 0; mt < 2; ++mt)
            #pragma unroll
            for (int nt = 0; nt < 4; ++nt)
                acc[mt][nt] = __builtin_amdgcn_mfma_f32_16x16x32_bf16(
                    fa[mt], fb[nt], acc[mt][nt], 0, 0, 0);
        if (step < 7) {
            #pragma unroll
            for (int mt = 0; mt < 2; ++mt) fa[mt] = na[mt];
            #pragma unroll
            for (int nt = 0; nt < 4; ++nt) fb[nt] = nb[nt];
        }
    }

    // Scatter: C/D layout col = lane&15, row = (lane>>4)*4 + reg (verified).
    int hr[2][4]; float sr[2][4]; int hc[4]; float sc[4];
    #pragma unroll
    for (int mt = 0; mt < 2; ++mt)
        #pragma unroll
        for (int rg = 0; rg < 4; ++rg) {
            int c1 = i0 + mt * 16 + (l >> 4) * 4 + rg;
            hr[mt][rg] = h[c1]; sr[mt][rg] = s[c1];
        }
    #pragma unroll
    for (int nt = 0; nt < 4; ++nt) {
        int c2 = j0 + nt * 16 + (l & 15);
        hc[nt] = h[C_DIM + c2]; sc[nt] = s[C_DIM + c2];
    }
    #pragma unroll
    for (int mt = 0; mt < 2; ++mt)
        #pragma unroll
        for (int nt = 0; nt < 4; ++nt)
            #pragma unroll
            for (int rg = 0; rg < 4; ++rg) {
                int bin = hr[mt][rg] + hc[nt];
                if (bin >= D_DIM) bin -= D_DIM;
                atomicAdd(&hist[bin], sr[mt][rg] * sc[nt] * acc[mt][nt][rg]);
            }
    __syncthreads();

    // Flush: plain coalesced float4 stores to this block's partial slice.
    const int slot = b * 16 + ib * 4 + jb;
    float* pb = part + (size_t)slot * D_DIM;
    #pragma unroll
    for (int l4 = 0; l4 < 4; ++l4) {
        int i4 = l4 * 512 + tid;
        if (i4 < D_DIM / 4)
            ((float4*)pb)[i4] = ((const float4*)hist)[i4];
    }
}

// ---------------------------------------------------------------------------
// Kernel 3: reduce the 16 partials of each batch -> out[b, d]. float4 loads,
// plain stores; fully overwrites out (no memset needed).
// ---------------------------------------------------------------------------
__global__ __launch_bounds__(256) void reduce_part(
    const float* __restrict__ part, float* __restrict__ out) {
    int i4 = blockIdx.x * 256 + threadIdx.x;     // over B*D/4 = 32000
    if (i4 >= B_DIM * D_DIM / 4) return;
    int b = i4 / (D_DIM / 4);
    int d = i4 - b * (D_DIM / 4);
    const float4* p = (const float4*)(part + (size_t)b * 16 * D_DIM) + d;
    float4 v = {0.f, 0.f, 0.f, 0.f};
    #pragma unroll
    for (int t = 0; t < 16; ++t) {
        float4 q = p[(size_t)t * (D_DIM / 4)];
        v.x += q.x; v.y += q.y; v.z += q.z; v.w += q.w;
    }
    ((float4*)out)[i4] = v;
}

extern "C" void kernel_launch(void* const* d_in, const int* in_sizes, int n_in,
                              void* d_out, int out_size, void* d_ws, size_t ws_size,
                              hipStream_t stream) {
    const float* x  = (const float*)d_in[0];  // [16, 512, 14, 14] fp32
    const float* S1 = (const float*)d_in[1];  // [512, 8000] fp32
    const float* S2 = (const float*)d_in[2];  // [512, 8000] fp32
    float* out = (float*)d_out;               // [16, 8000] fp32

    // ws: h[1024] int | s[1024] f32 | xp[8192*224] bf16 (3.7 MB)
    //   | part[256*8000] f32 (8.2 MB)
    int*            h    = (int*)d_ws;
    float*          s    = (float*)(h + 2 * C_DIM);
    unsigned short* xp   = (unsigned short*)(s + 2 * C_DIM);
    float*          part = (float*)(xp + (size_t)NROW * KP);

    prep<<<1024, 256, 0, stream>>>(x, S1, S2, h, s, xp);

    dim3 grid(4, 4, B_DIM);                   // 256 blocks, 128x128 tiles
    gram_hist<<<grid, 512, 0, stream>>>(xp, h, s, part);

    reduce_part<<<(B_DIM * D_DIM / 4 + 255) / 256, 256, 0, stream>>>(part, out);
}